// Round 11
// baseline (90.587 us; speedup 1.0000x reference)
//
#include <hip/hip_runtime.h>

#define NBUCK 64
#define NCLS 12              // 7 + 3 + 2 class-instances (class 11 derived, not stored)
#define NBMAIN 576           // 147456 4-px groups / 256 groups-per-block
#define NPART 16             // replicated global partials (576/16 = 36 blocks each)
#define NENT (NCLS*NBUCK)    // 768 entries
#define IGNORE_LBL 255
#define PIX (4*384*384)

// unaligned-capable float4 (global dwordx4 needs only 4B alignment)
typedef float float4a __attribute__((ext_vector_type(4), aligned(4)));

// ws layout (memset to 0 each call, 49,408 B):
//  0:    u32    done
//  16:   double ce_acc[8][3]            192 B   (nll, nll2, valid)
//  256:  u32    pcnt[NPART][NENT]    49,152 B   packed (cnt<<16)|fg
// worst-case per entry per part: 36 blocks * 1024 px = 36,864 < 2^16 -> packing safe.

__global__ __launch_bounds__(512) void k_main(
    const float* __restrict__ p0, const float* __restrict__ p1,
    const float* __restrict__ p2, const float* __restrict__ pdsn,
    const int* __restrict__ t0, const int* __restrict__ t1, const int* __restrict__ t2,
    unsigned int* __restrict__ done, double* __restrict__ ce_acc,
    unsigned int* __restrict__ pcnt, float* __restrict__ out)
{
    __shared__ unsigned int h[NENT];             // 3 KB
    __shared__ float cw[8][3];
    __shared__ unsigned int is_last;
    int t = threadIdx.x;
    for (int i = t; i < NENT; i += 512) h[i] = 0u;
    __syncthreads();

    int role = t >> 8;                           // wave-granular role split
    int lt = t & 255;
    int g = blockIdx.x * 256 + lt;               // 4-px group id
    int gx = g % 96;
    int row = g / 96;
    int y = row % 384;
    int b = row / 384;
    int x4 = gx * 4;

    const float scale = 95.0f / 383.0f;          // align_corners=True, 96 -> 384
    float sy = y * scale;
    int y0 = (int)sy; if (y0 > 94) y0 = 94;
    float ty = sy - (float)y0;
    float oty = 1.0f - ty;
    float sx0 = (float)x4 * scale;
    int X0 = (int)sx0; if (X0 > 92) X0 = 92;     // cols X0..X0+3 cover all 4 px

    // tent weights (exact bilinear), pre-scaled by vertical weights
    float Wa[4][4], Wb[4][4];
    #pragma unroll
    for (int i = 0; i < 4; i++) {
        float sx = (float)(x4 + i) * scale;
        #pragma unroll
        for (int j = 0; j < 4; j++) {
            float w = fmaxf(1.0f - fabsf(sx - (float)(X0 + j)), 0.0f);
            Wa[i][j] = w * oty;
            Wb[i][j] = w * ty;
        }
    }

    const int rb = y0 * 96 + X0;

    auto interp4 = [&](const float* A, int c, float zout[4]) {
        float4a r0 = *(const float4a*)(A + c * 9216);
        float4a r1 = *(const float4a*)(A + c * 9216 + 96);
        #pragma unroll
        for (int i = 0; i < 4; i++) {
            zout[i] = r0.x*Wa[i][0] + r0.y*Wa[i][1] + r0.z*Wa[i][2] + r0.w*Wa[i][3]
                    + r1.x*Wb[i][0] + r1.y*Wb[i][1] + r1.z*Wb[i][2] + r1.w*Wb[i][3];
        }
    };
    auto histadd = [&](int cls, int fg, float err) {
        int bk = (int)(err * (float)NBUCK);
        if (bk > NBUCK - 1) bk = NBUCK - 1;
        atomicAdd(&h[cls * NBUCK + bk], 0x10000u | (unsigned)fg);
    };

    float nll = 0.f, nll2 = 0.f; int vc = 0;

    int4 L0 = *(const int4*)(t0 + g * 4);
    int l0v[4] = {L0.x, L0.y, L0.z, L0.w};

    // |z| <= ~7 (bilinear blends of N(0,1)): exp of diffs overflow-safe in fp32.
    if (role == 0) {
        // ---- branch 0: 7 classes (CE + lovasz); softmax via diffs (6 exps/px) ----
        const float* A0 = p0 + b * 7 * 9216 + rb;
        float z0[7][4];
        #pragma unroll
        for (int c = 0; c < 7; c++) interp4(A0, c, z0[c]);
        #pragma unroll
        for (int i = 0; i < 4; i++) {
            int l = l0v[i];
            if (l != IGNORE_LBL) {
                float e[7]; e[0] = 1.0f; float s = 1.0f;
                #pragma unroll
                for (int c = 1; c < 7; c++) { e[c] = __expf(z0[c][i] - z0[0][i]); s += e[c]; }
                float inv = 1.0f / s;
                float zl = z0[0][i];
                #pragma unroll
                for (int c = 1; c < 7; c++) zl = (l == c) ? z0[c][i] : zl;
                nll += __logf(s) - (zl - z0[0][i]);
                vc++;
                #pragma unroll
                for (int c = 0; c < 7; c++) {
                    int fg = (l == c);
                    histadd(c, fg, fabsf((float)fg - e[c] * inv));
                }
            }
        }
    } else {
        // ---- DSN: 7 classes, CE only, logsumexp via diffs (6 exps/px) ----
        const float* Ad = pdsn + b * 7 * 9216 + rb;
        float zd[7][4];
        #pragma unroll
        for (int c = 0; c < 7; c++) interp4(Ad, c, zd[c]);
        #pragma unroll
        for (int i = 0; i < 4; i++) {
            int l = l0v[i];
            if (l != IGNORE_LBL) {
                float s = 1.0f;
                #pragma unroll
                for (int c = 1; c < 7; c++) s += __expf(zd[c][i] - zd[0][i]);
                float zl = zd[0][i];
                #pragma unroll
                for (int c = 1; c < 7; c++) zl = (l == c) ? zd[c][i] : zl;
                nll2 += __logf(s) - (zl - zd[0][i]);
            }
        }

        int4 L1 = *(const int4*)(t1 + g * 4);
        int l1v[4] = {L1.x, L1.y, L1.z, L1.w};

        // ---- branch 1: 3 classes (2 exps/px) ----
        const float* A1 = p1 + b * 3 * 9216 + rb;
        float z1[3][4];
        #pragma unroll
        for (int c = 0; c < 3; c++) interp4(A1, c, z1[c]);
        #pragma unroll
        for (int i = 0; i < 4; i++) {
            int l = l1v[i];
            if (l != IGNORE_LBL) {
                float e1 = __expf(z1[1][i] - z1[0][i]);
                float e2 = __expf(z1[2][i] - z1[0][i]);
                float inv = 1.0f / (1.0f + e1 + e2);
                histadd(7 + 0, (l == 0), fabsf((float)(l == 0) - inv));
                histadd(7 + 1, (l == 1), fabsf((float)(l == 1) - e1 * inv));
                histadd(7 + 2, (l == 2), fabsf((float)(l == 2) - e2 * inv));
            }
        }

        int4 L2 = *(const int4*)(t2 + g * 4);
        int l2v[4] = {L2.x, L2.y, L2.z, L2.w};

        // ---- branch 2: 2 classes, only class 10 stored (1 exp/px) ----
        const float* A2 = p2 + b * 2 * 9216 + rb;
        float z2a[2][4];
        #pragma unroll
        for (int c = 0; c < 2; c++) interp4(A2, c, z2a[c]);
        #pragma unroll
        for (int i = 0; i < 4; i++) {
            int l = l2v[i];
            if (l != IGNORE_LBL) {
                float p0c = 1.0f / (1.0f + __expf(z2a[1][i] - z2a[0][i]));
                histadd(10, (l == 0), fabsf((float)(l == 0) - p0c));
            }
        }
    }

    // ---- CE block reduce: role A carries nll/vc, role B carries nll2 ----
    #pragma unroll
    for (int o = 32; o > 0; o >>= 1) {
        nll  += __shfl_down(nll, o);
        nll2 += __shfl_down(nll2, o);
        vc   += __shfl_down(vc, o);
    }
    int wv = t >> 6, ln = t & 63;
    if (ln == 0) { cw[wv][0] = nll; cw[wv][1] = nll2; cw[wv][2] = (float)vc; }
    __syncthreads();                                  // also fences all LDS atomics

    // ---- CE: replicated double accumulators (contention 72/address) ----
    if (t == 0) {
        float a = 0.f, bb = 0.f, cc = 0.f;
        #pragma unroll
        for (int w = 0; w < 8; w++) { a += cw[w][0]; bb += cw[w][1]; cc += cw[w][2]; }
        double* ca = ce_acc + (blockIdx.x & 7) * 3;
        atomicAdd(&ca[0], (double)a);
        atomicAdd(&ca[1], (double)bb);
        atomicAdd(&ca[2], (double)cc);
    }

    // ---- flush nonzero buckets into 1-of-16 replicated global partials ----
    unsigned int* pp = pcnt + (size_t)(blockIdx.x & (NPART - 1)) * NENT;
    for (int i = t; i < NENT; i += 512) {
        unsigned int v = h[i];
        if (v) atomicAdd(&pp[i], v);
    }

    // ---- signal; last block inlines merge + walk + combine ----
    __threadfence();
    __syncthreads();
    if (t == 0) is_last = (atomicAdd(done, 1u) == NBMAIN - 1) ? 1u : 0u;
    __syncthreads();
    if (!is_last) return;
    __threadfence();

    // ======== TAIL (one block, 512 threads) ========
    __shared__ double cef[24];
    __shared__ float ce_tot[3];
    __shared__ unsigned long long sc[512];
    __shared__ float sf[512];
    __shared__ float cls_lov[NCLS];
    __shared__ float cls_pres[NCLS];

    if (t < 24) cef[t] = atomicAdd(&ce_acc[t], 0.0);   // coherent read
    __syncthreads();
    if (t == 0) {
        double a = 0, bb = 0, cc = 0;
        #pragma unroll
        for (int w = 0; w < 8; w++) { a += cef[w*3]; bb += cef[w*3+1]; cc += cef[w*3+2]; }
        ce_tot[0] = (float)a; ce_tot[1] = (float)bb; ce_tot[2] = (float)cc;
    }

    // lovasz walk: 8 classes per round (segmented 64-thread scans), 2 rounds
    int sub = t >> 6;                 // segment 0..7
    int p   = t & 63;                 // position in segment
    int bk  = NBUCK - 1 - p;          // descending bucket

    for (int r = 0; r < 2; r++) {
        int kk = r * 8 + sub;         // 0..7, then 8..15 (12..15 idle)
        unsigned int cnt = 0, fg = 0;
        if (kk < NCLS) {
            int src = (kk == 11) ? 10 : kk;      // class 11 derived from class 10
            #pragma unroll
            for (int cy = 0; cy < NPART; cy++) {
                unsigned int v = atomicAdd(&pcnt[(size_t)cy * NENT + src * NBUCK + bk], 0u);
                cnt += v >> 16; fg += v & 0xffffu;
            }
            if (kk == 11) fg = cnt - fg;
        }
        unsigned long long own = ((unsigned long long)cnt << 32) | fg;
        __syncthreads();
        sc[t] = own;
        __syncthreads();
        #pragma unroll
        for (int o = 1; o < 64; o <<= 1) {
            unsigned long long add = (p >= o) ? sc[t - o] : 0ull;
            __syncthreads();
            sc[t] += add;
            __syncthreads();
        }
        unsigned long long total = sc[(sub << 6) + 63];
        unsigned long long excl = sc[t] - own;
        unsigned int G = (unsigned int)(total & 0xffffffffu);

        float contrib = 0.f;
        if (G > 0 && cnt > 0) {
            unsigned int rr = (unsigned int)(excl >> 32);
            unsigned int F  = (unsigned int)(excl & 0xffffffffu);
            float fG = (float)G;
            float j0 = 1.0f - (fG - (float)F) / fmaxf(fG + (float)rr - (float)F, 1.0f);
            rr += cnt; F += fg;
            float j1 = 1.0f - (fG - (float)F) / fmaxf(fG + (float)rr - (float)F, 1.0f);
            contrib = (((float)bk + 0.5f) * (1.0f / (float)NBUCK)) * (j1 - j0);
        }
        sf[t] = contrib;
        __syncthreads();
        #pragma unroll
        for (int o = 32; o > 0; o >>= 1) {
            if (p < o) sf[t] += sf[t + o];
            __syncthreads();
        }
        if (p == 0 && kk < NCLS) {
            cls_lov[kk]  = (G > 0) ? sf[t] : 0.f;
            cls_pres[kk] = (G > 0) ? 1.f : 0.f;
        }
    }
    __syncthreads();

    if (t == 0) {
        float l0 = 0.f, p0c = 0.f, l1 = 0.f, p1c = 0.f, l2 = 0.f, p2c = 0.f;
        for (int k = 0; k < 7;  k++) { l0 += cls_lov[k]; p0c += cls_pres[k]; }
        for (int k = 7; k < 10; k++) { l1 += cls_lov[k]; p1c += cls_pres[k]; }
        for (int k = 10; k < 12; k++) { l2 += cls_lov[k]; p2c += cls_pres[k]; }
        float vcnt = fmaxf(ce_tot[2], 1.0f);
        out[0] = ce_tot[0] / vcnt
               + l0 / fmaxf(p0c, 1.f)
               + 0.4f * (l1 / fmaxf(p1c, 1.f))
               + 0.4f * (l2 / fmaxf(p2c, 1.f))
               + 0.4f * (ce_tot[1] / vcnt);
    }
}

extern "C" void kernel_launch(void* const* d_in, const int* in_sizes, int n_in,
                              void* d_out, int out_size, void* d_ws, size_t ws_size,
                              hipStream_t stream)
{
    const float* p0 = (const float*)d_in[0];   // [4,7,96,96]
    const float* p1 = (const float*)d_in[1];   // [4,3,96,96]
    const float* p2 = (const float*)d_in[2];   // [4,2,96,96]
    const float* pd = (const float*)d_in[3];   // [4,7,96,96]
    const int* t0 = (const int*)d_in[4];       // [4,384,384]
    const int* t1 = (const int*)d_in[5];
    const int* t2 = (const int*)d_in[6];

    char* ws = (char*)d_ws;
    unsigned int* done = (unsigned int*)ws;                 // 4 B
    double* ce_acc = (double*)(ws + 16);                    // 192 B
    unsigned int* pcnt = (unsigned int*)(ws + 256);         // 49,152 B

    // zero control + accumulators (one small capturable node)
    hipMemsetAsync(d_ws, 0, 256 + (size_t)NPART * NENT * 4, stream);

    k_main<<<NBMAIN, 512, 0, stream>>>(p0, p1, p2, pd, t0, t1, t2,
                                       done, ce_acc, pcnt, (float*)d_out);
}

// Round 12
// 27.130 us; speedup vs baseline: 3.3390x; 3.3390x over previous
//
#include <hip/hip_runtime.h>

#define NBUCK 64
#define NCLS 12              // 7 + 3 + 2 class-instances (class 11 derived, not stored)
#define NCHUNK 16            // merge-tree fan-in chunks
#define NBMAIN 576           // 147456 4-px groups / 256 groups-per-block
#define SPC (NBMAIN / NCHUNK)   // 36 slices per merge chunk
#define NPLANES 19           // 7 (p0) + 7 (pdsn) + 3 (p1) + 2 (p2)
#define SROWS 3              // staged input rows per block: Y, Y+1, Y+2
#define IGNORE_LBL 255
#define PIX (4*384*384)

typedef float float4a  __attribute__((ext_vector_type(4), aligned(4)));
typedef float float4al __attribute__((ext_vector_type(4), aligned(16)));

// ws layout:
//  0:      u32    partial[NCHUNK][NCLS][NBUCK]    49,152 B
//  49152:  float4 ce_part[NBMAIN]                  9,216 B
//  58368:  u32    slices[NBMAIN][NCLS][NBUCK]  1,769,472 B

// 512 threads: role A (waves 0-3) = branch0 + main CE; role B (waves 4-7) = DSN + b1 + b2.
// All 19 input planes' 3 needed rows are staged to LDS with coalesced dwordx4 loads;
// bilinear reads then hit LDS (overlapping addrs broadcast) instead of per-lane TA gathers.
__global__ __launch_bounds__(512) void k_main(
    const float* __restrict__ p0, const float* __restrict__ p1,
    const float* __restrict__ p2, const float* __restrict__ pdsn,
    const int* __restrict__ t0, const int* __restrict__ t1, const int* __restrict__ t2,
    unsigned int* __restrict__ slices, float4* __restrict__ ce_part)
{
    __shared__ float stage[NPLANES * SROWS * 96];   // 21,888 B
    __shared__ unsigned int h[NCLS * NBUCK];        // 3 KB
    __shared__ float cw[8][3];
    int t = threadIdx.x;
    for (int i = t; i < NCLS * NBUCK; i += 512) h[i] = 0u;

    int g0 = blockIdx.x * 256;
    int row0 = g0 / 96;                  // blocks never straddle batch images (144/image)
    int ys = row0 % 384;
    int b = row0 / 384;

    const float scale = 95.0f / 383.0f;  // align_corners=True, 96 -> 384
    int Y = (int)((float)ys * scale);    // all y0 in this block are in {Y, Y+1}

    // ---- stage 19 planes x 3 rows x 96 floats (coalesced dwordx4) ----
    for (int q = t; q < NPLANES * SROWS * 24; q += 512) {
        int p = q / (SROWS * 24);
        int rem = q % (SROWS * 24);
        int r = rem / 24;
        int c4 = rem % 24;
        int gy = Y + r; if (gy > 95) gy = 95;
        const float* src;
        if (p < 7)       src = p0   + (b * 7 + p)        * 9216;
        else if (p < 14) src = pdsn + (b * 7 + (p - 7))  * 9216;
        else if (p < 17) src = p1   + (b * 3 + (p - 14)) * 9216;
        else             src = p2   + (b * 2 + (p - 17)) * 9216;
        *(float4al*)&stage[(p * SROWS + r) * 96 + c4 * 4] =
            *(const float4al*)(src + gy * 96 + c4 * 4);
    }
    __syncthreads();

    int role = t >> 8;                   // wave-granular role split
    int lt = t & 255;
    int g = g0 + lt;                     // 4-px group id
    int gx = g % 96;
    int row = g / 96;
    int y = row % 384;
    int x4 = gx * 4;

    float sy = (float)y * scale;
    int y0 = (int)sy; if (y0 > 94) y0 = 94;
    float ty = sy - (float)y0;
    float oty = 1.0f - ty;
    int ry = y0 - Y;                     // 0 or 1
    float sx0 = (float)x4 * scale;
    int X0 = (int)sx0; if (X0 > 92) X0 = 92;   // cols X0..X0+3 cover all 4 px

    // tent weights (exact bilinear), pre-scaled by vertical weights
    float Wa[4][4], Wb[4][4];
    #pragma unroll
    for (int i = 0; i < 4; i++) {
        float sx = (float)(x4 + i) * scale;
        #pragma unroll
        for (int j = 0; j < 4; j++) {
            float w = fmaxf(1.0f - fabsf(sx - (float)(X0 + j)), 0.0f);
            Wa[i][j] = w * oty;
            Wb[i][j] = w * ty;
        }
    }

    const int sb = ry * 96 + X0;         // LDS offset within a plane block

    auto interp4 = [&](int plane, float zout[4]) {
        const float* q = &stage[plane * (SROWS * 96) + sb];
        float4a r0 = *(const float4a*)q;
        float4a r1 = *(const float4a*)(q + 96);
        #pragma unroll
        for (int i = 0; i < 4; i++) {
            zout[i] = r0.x*Wa[i][0] + r0.y*Wa[i][1] + r0.z*Wa[i][2] + r0.w*Wa[i][3]
                    + r1.x*Wb[i][0] + r1.y*Wb[i][1] + r1.z*Wb[i][2] + r1.w*Wb[i][3];
        }
    };
    auto histadd = [&](int cls, int fg, float err) {
        int bk = (int)(err * (float)NBUCK);
        if (bk > NBUCK - 1) bk = NBUCK - 1;
        atomicAdd(&h[cls * NBUCK + bk], 0x10000u | (unsigned)fg);
    };

    float nll = 0.f, nll2 = 0.f; int vc = 0;

    int4 L0 = *(const int4*)(t0 + g * 4);
    int l0v[4] = {L0.x, L0.y, L0.z, L0.w};

    // |z| <= ~7 (bilinear blends of N(0,1)): exp of diffs overflow-safe in fp32.
    if (role == 0) {
        // ---- branch 0: 7 classes (CE + lovasz); softmax via diffs (6 exps/px) ----
        float z0[7][4];
        #pragma unroll
        for (int c = 0; c < 7; c++) interp4(c, z0[c]);
        #pragma unroll
        for (int i = 0; i < 4; i++) {
            int l = l0v[i];
            if (l != IGNORE_LBL) {
                float e[7]; e[0] = 1.0f; float s = 1.0f;
                #pragma unroll
                for (int c = 1; c < 7; c++) { e[c] = __expf(z0[c][i] - z0[0][i]); s += e[c]; }
                float inv = 1.0f / s;
                float zl = z0[0][i];
                #pragma unroll
                for (int c = 1; c < 7; c++) zl = (l == c) ? z0[c][i] : zl;
                nll += __logf(s) - (zl - z0[0][i]);
                vc++;
                #pragma unroll
                for (int c = 0; c < 7; c++) {
                    int fg = (l == c);
                    histadd(c, fg, fabsf((float)fg - e[c] * inv));
                }
            }
        }
    } else {
        // ---- DSN: 7 classes, CE only, logsumexp via diffs (6 exps/px) ----
        float zd[7][4];
        #pragma unroll
        for (int c = 0; c < 7; c++) interp4(7 + c, zd[c]);
        #pragma unroll
        for (int i = 0; i < 4; i++) {
            int l = l0v[i];
            if (l != IGNORE_LBL) {
                float s = 1.0f;
                #pragma unroll
                for (int c = 1; c < 7; c++) s += __expf(zd[c][i] - zd[0][i]);
                float zl = zd[0][i];
                #pragma unroll
                for (int c = 1; c < 7; c++) zl = (l == c) ? zd[c][i] : zl;
                nll2 += __logf(s) - (zl - zd[0][i]);
            }
        }

        int4 L1 = *(const int4*)(t1 + g * 4);
        int l1v[4] = {L1.x, L1.y, L1.z, L1.w};

        // ---- branch 1: 3 classes (2 exps/px) ----
        float z1[3][4];
        #pragma unroll
        for (int c = 0; c < 3; c++) interp4(14 + c, z1[c]);
        #pragma unroll
        for (int i = 0; i < 4; i++) {
            int l = l1v[i];
            if (l != IGNORE_LBL) {
                float e1 = __expf(z1[1][i] - z1[0][i]);
                float e2 = __expf(z1[2][i] - z1[0][i]);
                float inv = 1.0f / (1.0f + e1 + e2);
                histadd(7 + 0, (l == 0), fabsf((float)(l == 0) - inv));
                histadd(7 + 1, (l == 1), fabsf((float)(l == 1) - e1 * inv));
                histadd(7 + 2, (l == 2), fabsf((float)(l == 2) - e2 * inv));
            }
        }

        int4 L2 = *(const int4*)(t2 + g * 4);
        int l2v[4] = {L2.x, L2.y, L2.z, L2.w};

        // ---- branch 2: 2 classes, only class 10 stored (1 exp/px) ----
        float z2a[2][4];
        #pragma unroll
        for (int c = 0; c < 2; c++) interp4(17 + c, z2a[c]);
        #pragma unroll
        for (int i = 0; i < 4; i++) {
            int l = l2v[i];
            if (l != IGNORE_LBL) {
                float p0c = 1.0f / (1.0f + __expf(z2a[1][i] - z2a[0][i]));
                histadd(10, (l == 0), fabsf((float)(l == 0) - p0c));
            }
        }
    }

    // ---- CE block reduce: role A carries nll/vc, role B carries nll2 ----
    #pragma unroll
    for (int o = 32; o > 0; o >>= 1) {
        nll  += __shfl_down(nll, o);
        nll2 += __shfl_down(nll2, o);
        vc   += __shfl_down(vc, o);
    }
    int wv = t >> 6, ln = t & 63;
    if (ln == 0) { cw[wv][0] = nll; cw[wv][1] = nll2; cw[wv][2] = (float)vc; }
    __syncthreads();                                  // also fences all LDS atomics
    if (t == 0) {
        float a = 0.f, bb = 0.f, cc = 0.f;
        #pragma unroll
        for (int w = 0; w < 8; w++) { a += cw[w][0]; bb += cw[w][1]; cc += cw[w][2]; }
        ce_part[blockIdx.x] = make_float4(a, bb, cc, 0.f);
    }

    // ---- flush block-private histogram (plain coalesced stores) ----
    unsigned int* dst = slices + (size_t)blockIdx.x * (NCLS * NBUCK);
    for (int i = t; i < NCLS * NBUCK; i += 512) dst[i] = h[i];
}

// parallel fan-in: 12 classes x 16 chunks; each block sums 36 slices.
// per-chunk per-bucket count <= PIX/NCHUNK = 36,864 < 2^16 -> u16 packing safe.
__global__ __launch_bounds__(64) void k_merge(
    const unsigned int* __restrict__ slices, unsigned int* __restrict__ partial)
{
    int kk = blockIdx.x % NCLS;
    int cy = blockIdx.x / NCLS;
    int bk = threadIdx.x;
    int s0 = cy * SPC;
    unsigned int acc = 0;
    for (int s = 0; s < SPC; s++)
        acc += slices[(size_t)((s0 + s) * NCLS + kk) * NBUCK + bk];
    partial[(size_t)(cy * NCLS + kk) * NBUCK + bk] = acc;
}

// single block: CE totals + 2 rounds x 8-class segmented scan-walk + final combine.
__global__ __launch_bounds__(512) void k_fin(
    const unsigned int* __restrict__ partial, const float4* __restrict__ ce_part,
    float* __restrict__ out)
{
    int t = threadIdx.x;
    __shared__ float ce_tot[3];
    __shared__ float cwf[8][3];
    __shared__ unsigned long long sc[512];
    __shared__ float sf[512];
    __shared__ float cls_lov[NCLS];
    __shared__ float cls_pres[NCLS];

    // Phase A: CE totals from per-block partials
    float a = 0.f, bb = 0.f, cc = 0.f;
    for (int e = t; e < NBMAIN; e += 512) {
        float4 v = ce_part[e];
        a += v.x; bb += v.y; cc += v.z;
    }
    #pragma unroll
    for (int o = 32; o > 0; o >>= 1) {
        a += __shfl_down(a, o); bb += __shfl_down(bb, o); cc += __shfl_down(cc, o);
    }
    if ((t & 63) == 0) { cwf[t >> 6][0] = a; cwf[t >> 6][1] = bb; cwf[t >> 6][2] = cc; }
    __syncthreads();
    if (t == 0) {
        float x = 0.f, y = 0.f, z = 0.f;
        for (int w = 0; w < 8; w++) { x += cwf[w][0]; y += cwf[w][1]; z += cwf[w][2]; }
        ce_tot[0] = x; ce_tot[1] = y; ce_tot[2] = z;
    }

    // Phase B: lovasz walk, 8 classes per round (segmented 64-thread scans), 2 rounds.
    int sub = t >> 6;                 // segment 0..7
    int p   = t & 63;                 // position in segment
    int bk  = NBUCK - 1 - p;          // descending bucket

    for (int r = 0; r < 2; r++) {
        int kk = r * 8 + sub;         // 0..7, then 8..15 (12..15 idle)
        unsigned int cnt = 0, fg = 0;
        if (kk < NCLS) {
            int src = (kk == 11) ? 10 : kk;      // class 11 derived from class 10
            #pragma unroll
            for (int cy = 0; cy < NCHUNK; cy++) {
                unsigned int v = partial[(size_t)(cy * NCLS + src) * NBUCK + bk];
                cnt += v >> 16; fg += v & 0xffffu;
            }
            if (kk == 11) fg = cnt - fg;
        }
        unsigned long long own = ((unsigned long long)cnt << 32) | fg;
        __syncthreads();
        sc[t] = own;
        __syncthreads();
        #pragma unroll
        for (int o = 1; o < 64; o <<= 1) {
            unsigned long long add = (p >= o) ? sc[t - o] : 0ull;
            __syncthreads();
            sc[t] += add;
            __syncthreads();
        }
        unsigned long long total = sc[(sub << 6) + 63];
        unsigned long long excl = sc[t] - own;
        unsigned int G = (unsigned int)(total & 0xffffffffu);

        float contrib = 0.f;
        if (G > 0 && cnt > 0) {
            unsigned int rr = (unsigned int)(excl >> 32);
            unsigned int F  = (unsigned int)(excl & 0xffffffffu);
            float fG = (float)G;
            float j0 = 1.0f - (fG - (float)F) / fmaxf(fG + (float)rr - (float)F, 1.0f);
            rr += cnt; F += fg;
            float j1 = 1.0f - (fG - (float)F) / fmaxf(fG + (float)rr - (float)F, 1.0f);
            contrib = (((float)bk + 0.5f) * (1.0f / (float)NBUCK)) * (j1 - j0);
        }
        sf[t] = contrib;
        __syncthreads();
        #pragma unroll
        for (int o = 32; o > 0; o >>= 1) {
            if (p < o) sf[t] += sf[t + o];
            __syncthreads();
        }
        if (p == 0 && kk < NCLS) {
            cls_lov[kk]  = (G > 0) ? sf[t] : 0.f;
            cls_pres[kk] = (G > 0) ? 1.f : 0.f;
        }
    }
    __syncthreads();

    if (t == 0) {
        float l0 = 0.f, p0c = 0.f, l1 = 0.f, p1c = 0.f, l2 = 0.f, p2c = 0.f;
        for (int k = 0; k < 7;  k++) { l0 += cls_lov[k]; p0c += cls_pres[k]; }
        for (int k = 7; k < 10; k++) { l1 += cls_lov[k]; p1c += cls_pres[k]; }
        for (int k = 10; k < 12; k++) { l2 += cls_lov[k]; p2c += cls_pres[k]; }
        float vcnt = fmaxf(ce_tot[2], 1.0f);
        out[0] = ce_tot[0] / vcnt
               + l0 / fmaxf(p0c, 1.f)
               + 0.4f * (l1 / fmaxf(p1c, 1.f))
               + 0.4f * (l2 / fmaxf(p2c, 1.f))
               + 0.4f * (ce_tot[1] / vcnt);
    }
}

extern "C" void kernel_launch(void* const* d_in, const int* in_sizes, int n_in,
                              void* d_out, int out_size, void* d_ws, size_t ws_size,
                              hipStream_t stream)
{
    const float* p0 = (const float*)d_in[0];   // [4,7,96,96]
    const float* p1 = (const float*)d_in[1];   // [4,3,96,96]
    const float* p2 = (const float*)d_in[2];   // [4,2,96,96]
    const float* pd = (const float*)d_in[3];   // [4,7,96,96]
    const int* t0 = (const int*)d_in[4];       // [4,384,384]
    const int* t1 = (const int*)d_in[5];
    const int* t2 = (const int*)d_in[6];

    char* ws = (char*)d_ws;
    const size_t partial_bytes = (size_t)NCHUNK * NCLS * NBUCK * 4;     // 49,152
    const size_t cepart_bytes = (size_t)NBMAIN * 16;                    // 9,216
    unsigned int* partial = (unsigned int*)ws;
    float4* ce_part = (float4*)(ws + partial_bytes);
    unsigned int* slices = (unsigned int*)(ws + partial_bytes + cepart_bytes);

    k_main<<<NBMAIN, 512, 0, stream>>>(p0, p1, p2, pd, t0, t1, t2, slices, ce_part);
    k_merge<<<NCLS * NCHUNK, 64, 0, stream>>>(slices, partial);
    k_fin<<<1, 512, 0, stream>>>(partial, ce_part, (float*)d_out);
}

// Round 13
// 25.591 us; speedup vs baseline: 3.5398x; 1.0602x over previous
//
#include <hip/hip_runtime.h>

#define NBUCK 32
#define NCLS 12              // 7 + 3 + 2 class-instances (class 11 derived, not stored)
#define NCHUNK 16            // merge-tree fan-in chunks
#define NBMAIN 1152          // 147456 4-px groups / 128 groups-per-block
#define SPC (NBMAIN / NCHUNK)   // 72 slices per merge chunk
#define NENT (NCLS * NBUCK)  // 384
#define IGNORE_LBL 255
#define PIX (4*384*384)

// unaligned-capable float4 (global dwordx4 needs only 4B alignment)
typedef float float4a __attribute__((ext_vector_type(4), aligned(4)));

// ws layout:
//  0:      u32    partial[NCHUNK][NCLS][NBUCK]    24,576 B
//  24576:  float4 ce_part[NBMAIN]                 18,432 B
//  43008:  u32    slices[NBMAIN][NCLS][NBUCK]  1,769,472 B

// 128 threads, 1 four-px group per thread. 1152 blocks -> 4.5 blocks/CU:
// block-generation quantization waste ~11% (vs ~33% at 576x512/256).
__global__ __launch_bounds__(128) void k_main(
    const float* __restrict__ p0, const float* __restrict__ p1,
    const float* __restrict__ p2, const float* __restrict__ pdsn,
    const int* __restrict__ t0, const int* __restrict__ t1, const int* __restrict__ t2,
    unsigned int* __restrict__ slices, float4* __restrict__ ce_part)
{
    __shared__ unsigned int h[NENT];             // 1.5 KB
    __shared__ float cw[2][3];
    int t = threadIdx.x;
    #pragma unroll
    for (int i = t; i < NENT; i += 128) h[i] = 0u;
    __syncthreads();

    int g = blockIdx.x * 128 + t;                // 4-px group id (147456 total)
    int gx = g % 96;
    int row = g / 96;
    int y = row % 384;
    int b = row / 384;
    int x4 = gx * 4;

    const float scale = 95.0f / 383.0f;          // align_corners=True, 96 -> 384
    float sy = y * scale;
    int y0 = (int)sy; if (y0 > 94) y0 = 94;
    float ty = sy - (float)y0;
    float oty = 1.0f - ty;
    float sx0 = (float)x4 * scale;
    int X0 = (int)sx0; if (X0 > 92) X0 = 92;     // cols X0..X0+3 cover all 4 px

    // tent weights (exact bilinear), pre-scaled by vertical weights
    float Wa[4][4], Wb[4][4];
    #pragma unroll
    for (int i = 0; i < 4; i++) {
        float sx = (float)(x4 + i) * scale;
        #pragma unroll
        for (int j = 0; j < 4; j++) {
            float w = fmaxf(1.0f - fabsf(sx - (float)(X0 + j)), 0.0f);
            Wa[i][j] = w * oty;
            Wb[i][j] = w * ty;
        }
    }

    const int rb = y0 * 96 + X0;

    auto interp4 = [&](const float* A, int c, float zout[4]) {
        float4a r0 = *(const float4a*)(A + c * 9216);
        float4a r1 = *(const float4a*)(A + c * 9216 + 96);
        #pragma unroll
        for (int i = 0; i < 4; i++) {
            zout[i] = r0.x*Wa[i][0] + r0.y*Wa[i][1] + r0.z*Wa[i][2] + r0.w*Wa[i][3]
                    + r1.x*Wb[i][0] + r1.y*Wb[i][1] + r1.z*Wb[i][2] + r1.w*Wb[i][3];
        }
    };
    auto histadd = [&](int cls, int fg, float err) {
        int bk = (int)(err * (float)NBUCK);
        if (bk > NBUCK - 1) bk = NBUCK - 1;
        atomicAdd(&h[cls * NBUCK + bk], 0x10000u | (unsigned)fg);
    };

    float nll = 0.f, nll2 = 0.f; int vc = 0;

    int4 L0 = *(const int4*)(t0 + g * 4);
    int l0v[4] = {L0.x, L0.y, L0.z, L0.w};

    // |z| <= ~7 (bilinear blends of N(0,1)): exp of diffs overflow-safe in fp32.
    // ---- branch 0: 7 classes (CE + lovasz); softmax via diffs (6 exps/px) ----
    {
        const float* A0 = p0 + b * 7 * 9216 + rb;
        float z0[7][4];
        #pragma unroll
        for (int c = 0; c < 7; c++) interp4(A0, c, z0[c]);
        #pragma unroll
        for (int i = 0; i < 4; i++) {
            int l = l0v[i];
            if (l != IGNORE_LBL) {
                float e[7]; e[0] = 1.0f; float s = 1.0f;
                #pragma unroll
                for (int c = 1; c < 7; c++) { e[c] = __expf(z0[c][i] - z0[0][i]); s += e[c]; }
                float inv = 1.0f / s;
                float zl = z0[0][i];
                #pragma unroll
                for (int c = 1; c < 7; c++) zl = (l == c) ? z0[c][i] : zl;
                nll += __logf(s) - (zl - z0[0][i]);
                vc++;
                #pragma unroll
                for (int c = 0; c < 7; c++) {
                    int fg = (l == c);
                    histadd(c, fg, fabsf((float)fg - e[c] * inv));
                }
            }
        }
    }

    // ---- DSN: 7 classes, CE only, logsumexp via diffs (6 exps/px) ----
    {
        const float* Ad = pdsn + b * 7 * 9216 + rb;
        float zd[7][4];
        #pragma unroll
        for (int c = 0; c < 7; c++) interp4(Ad, c, zd[c]);
        #pragma unroll
        for (int i = 0; i < 4; i++) {
            int l = l0v[i];
            if (l != IGNORE_LBL) {
                float s = 1.0f;
                #pragma unroll
                for (int c = 1; c < 7; c++) s += __expf(zd[c][i] - zd[0][i]);
                float zl = zd[0][i];
                #pragma unroll
                for (int c = 1; c < 7; c++) zl = (l == c) ? zd[c][i] : zl;
                nll2 += __logf(s) - (zl - zd[0][i]);
            }
        }
    }

    // ---- branch 1: 3 classes (2 exps/px) ----
    {
        int4 L1 = *(const int4*)(t1 + g * 4);
        int l1v[4] = {L1.x, L1.y, L1.z, L1.w};
        const float* A1 = p1 + b * 3 * 9216 + rb;
        float z1[3][4];
        #pragma unroll
        for (int c = 0; c < 3; c++) interp4(A1, c, z1[c]);
        #pragma unroll
        for (int i = 0; i < 4; i++) {
            int l = l1v[i];
            if (l != IGNORE_LBL) {
                float e1 = __expf(z1[1][i] - z1[0][i]);
                float e2 = __expf(z1[2][i] - z1[0][i]);
                float inv = 1.0f / (1.0f + e1 + e2);
                histadd(7 + 0, (l == 0), fabsf((float)(l == 0) - inv));
                histadd(7 + 1, (l == 1), fabsf((float)(l == 1) - e1 * inv));
                histadd(7 + 2, (l == 2), fabsf((float)(l == 2) - e2 * inv));
            }
        }
    }

    // ---- branch 2: 2 classes, only class 10 stored (1 exp/px) ----
    {
        int4 L2 = *(const int4*)(t2 + g * 4);
        int l2v[4] = {L2.x, L2.y, L2.z, L2.w};
        const float* A2 = p2 + b * 2 * 9216 + rb;
        float z2a[2][4];
        #pragma unroll
        for (int c = 0; c < 2; c++) interp4(A2, c, z2a[c]);
        #pragma unroll
        for (int i = 0; i < 4; i++) {
            int l = l2v[i];
            if (l != IGNORE_LBL) {
                float p0c = 1.0f / (1.0f + __expf(z2a[1][i] - z2a[0][i]));
                histadd(10, (l == 0), fabsf((float)(l == 0) - p0c));
            }
        }
    }

    // ---- CE block reduce (2 waves) ----
    #pragma unroll
    for (int o = 32; o > 0; o >>= 1) {
        nll  += __shfl_down(nll, o);
        nll2 += __shfl_down(nll2, o);
        vc   += __shfl_down(vc, o);
    }
    int wv = t >> 6, ln = t & 63;
    if (ln == 0) { cw[wv][0] = nll; cw[wv][1] = nll2; cw[wv][2] = (float)vc; }
    __syncthreads();                                  // also fences all LDS atomics
    if (t == 0) {
        ce_part[blockIdx.x] = make_float4(cw[0][0] + cw[1][0],
                                          cw[0][1] + cw[1][1],
                                          cw[0][2] + cw[1][2], 0.f);
    }

    // ---- flush block-private histogram (plain coalesced stores) ----
    unsigned int* dst = slices + (size_t)blockIdx.x * NENT;
    #pragma unroll
    for (int i = t; i < NENT; i += 128) dst[i] = h[i];
}

// parallel fan-in: 12 classes x 16 chunks; each block sums 72 slices.
// per-chunk per-bucket count <= 72 blocks * 512 px = 36,864 < 2^16 -> u16 packing safe.
__global__ __launch_bounds__(32) void k_merge(
    const unsigned int* __restrict__ slices, unsigned int* __restrict__ partial)
{
    int kk = blockIdx.x % NCLS;
    int cy = blockIdx.x / NCLS;
    int bk = threadIdx.x;                // 0..31
    int s0 = cy * SPC;
    unsigned int acc = 0;
    for (int s = 0; s < SPC; s++)
        acc += slices[(size_t)(s0 + s) * NENT + kk * NBUCK + bk];
    partial[(size_t)(cy * NCLS + kk) * NBUCK + bk] = acc;
}

// single block: CE totals + ONE round of 16x32-wide segmented scan-walk + combine.
__global__ __launch_bounds__(512) void k_fin(
    const unsigned int* __restrict__ partial, const float4* __restrict__ ce_part,
    float* __restrict__ out)
{
    int t = threadIdx.x;
    __shared__ float ce_tot[3];
    __shared__ float cwf[8][3];
    __shared__ unsigned long long sc[512];
    __shared__ float sf[512];
    __shared__ float cls_lov[NCLS];
    __shared__ float cls_pres[NCLS];

    // Phase A: CE totals from per-block partials
    float a = 0.f, bb = 0.f, cc = 0.f;
    for (int e = t; e < NBMAIN; e += 512) {
        float4 v = ce_part[e];
        a += v.x; bb += v.y; cc += v.z;
    }
    #pragma unroll
    for (int o = 32; o > 0; o >>= 1) {
        a += __shfl_down(a, o); bb += __shfl_down(bb, o); cc += __shfl_down(cc, o);
    }
    if ((t & 63) == 0) { cwf[t >> 6][0] = a; cwf[t >> 6][1] = bb; cwf[t >> 6][2] = cc; }
    __syncthreads();
    if (t == 0) {
        float x = 0.f, y = 0.f, z = 0.f;
        for (int w = 0; w < 8; w++) { x += cwf[w][0]; y += cwf[w][1]; z += cwf[w][2]; }
        ce_tot[0] = x; ce_tot[1] = y; ce_tot[2] = z;
    }

    // Phase B: lovasz walk, all 12 classes in one round (16 segments x 32 threads)
    int sub = t >> 5;                 // segment 0..15 (12..15 idle)
    int p   = t & 31;                 // position in segment
    int bk  = NBUCK - 1 - p;          // descending bucket

    int kk = sub;
    unsigned int cnt = 0, fg = 0;
    if (kk < NCLS) {
        int src = (kk == 11) ? 10 : kk;          // class 11 derived from class 10
        #pragma unroll
        for (int cy = 0; cy < NCHUNK; cy++) {
            unsigned int v = partial[(size_t)(cy * NCLS + src) * NBUCK + bk];
            cnt += v >> 16; fg += v & 0xffffu;
        }
        if (kk == 11) fg = cnt - fg;
    }
    unsigned long long own = ((unsigned long long)cnt << 32) | fg;
    sc[t] = own;
    __syncthreads();
    #pragma unroll
    for (int o = 1; o < 32; o <<= 1) {
        unsigned long long add = (p >= o) ? sc[t - o] : 0ull;
        __syncthreads();
        sc[t] += add;
        __syncthreads();
    }
    unsigned long long total = sc[(sub << 5) + 31];
    unsigned long long excl = sc[t] - own;
    unsigned int G = (unsigned int)(total & 0xffffffffu);

    float contrib = 0.f;
    if (G > 0 && cnt > 0) {
        unsigned int rr = (unsigned int)(excl >> 32);
        unsigned int F  = (unsigned int)(excl & 0xffffffffu);
        float fG = (float)G;
        float j0 = 1.0f - (fG - (float)F) / fmaxf(fG + (float)rr - (float)F, 1.0f);
        rr += cnt; F += fg;
        float j1 = 1.0f - (fG - (float)F) / fmaxf(fG + (float)rr - (float)F, 1.0f);
        contrib = (((float)bk + 0.5f) * (1.0f / (float)NBUCK)) * (j1 - j0);
    }
    sf[t] = contrib;
    __syncthreads();
    #pragma unroll
    for (int o = 16; o > 0; o >>= 1) {
        if (p < o) sf[t] += sf[t + o];
        __syncthreads();
    }
    if (p == 0 && kk < NCLS) {
        cls_lov[kk]  = (G > 0) ? sf[t] : 0.f;
        cls_pres[kk] = (G > 0) ? 1.f : 0.f;
    }
    __syncthreads();

    if (t == 0) {
        float l0 = 0.f, p0c = 0.f, l1 = 0.f, p1c = 0.f, l2 = 0.f, p2c = 0.f;
        for (int k = 0; k < 7;  k++) { l0 += cls_lov[k]; p0c += cls_pres[k]; }
        for (int k = 7; k < 10; k++) { l1 += cls_lov[k]; p1c += cls_pres[k]; }
        for (int k = 10; k < 12; k++) { l2 += cls_lov[k]; p2c += cls_pres[k]; }
        float vcnt = fmaxf(ce_tot[2], 1.0f);
        out[0] = ce_tot[0] / vcnt
               + l0 / fmaxf(p0c, 1.f)
               + 0.4f * (l1 / fmaxf(p1c, 1.f))
               + 0.4f * (l2 / fmaxf(p2c, 1.f))
               + 0.4f * (ce_tot[1] / vcnt);
    }
}

extern "C" void kernel_launch(void* const* d_in, const int* in_sizes, int n_in,
                              void* d_out, int out_size, void* d_ws, size_t ws_size,
                              hipStream_t stream)
{
    const float* p0 = (const float*)d_in[0];   // [4,7,96,96]
    const float* p1 = (const float*)d_in[1];   // [4,3,96,96]
    const float* p2 = (const float*)d_in[2];   // [4,2,96,96]
    const float* pd = (const float*)d_in[3];   // [4,7,96,96]
    const int* t0 = (const int*)d_in[4];       // [4,384,384]
    const int* t1 = (const int*)d_in[5];
    const int* t2 = (const int*)d_in[6];

    char* ws = (char*)d_ws;
    const size_t partial_bytes = (size_t)NCHUNK * NENT * 4;             // 24,576
    const size_t cepart_bytes = (size_t)NBMAIN * 16;                    // 18,432
    unsigned int* partial = (unsigned int*)ws;
    float4* ce_part = (float4*)(ws + partial_bytes);
    unsigned int* slices = (unsigned int*)(ws + partial_bytes + cepart_bytes);

    k_main<<<NBMAIN, 128, 0, stream>>>(p0, p1, p2, pd, t0, t1, t2, slices, ce_part);
    k_merge<<<NCLS * NCHUNK, 32, 0, stream>>>(slices, partial);
    k_fin<<<1, 512, 0, stream>>>(partial, ce_part, (float*)d_out);
}

// Round 14
// 24.650 us; speedup vs baseline: 3.6749x; 1.0382x over previous
//
#include <hip/hip_runtime.h>

#define NBUCK 32
#define NCLS 12              // 7 + 3 + 2 class-instances (class 11 derived, not stored)
#define NBMAIN 1152          // 147456 4-px groups / 128 groups-per-block
#define NPART 16             // replicated global histogram copies
#define NENT (NCLS * NBUCK)  // 384
#define IGNORE_LBL 255
#define PIX (4*384*384)

// unaligned-capable float4 (global dwordx4 needs only 4B alignment)
typedef float float4a __attribute__((ext_vector_type(4), aligned(4)));

// ws layout:
//  0:      u32    pcnt[NPART][NENT]     24,576 B   (memset to 0 each call)
//  24576:  float4 ce_part[NBMAIN]       18,432 B   (plain stores, no init needed)
// per-entry per-replica count <= 72 blocks * 512 px = 36,864 < 2^16 -> packing safe.

__global__ __launch_bounds__(128) void k_main(
    const float* __restrict__ p0, const float* __restrict__ p1,
    const float* __restrict__ p2, const float* __restrict__ pdsn,
    const int* __restrict__ t0, const int* __restrict__ t1, const int* __restrict__ t2,
    unsigned int* __restrict__ pcnt, float4* __restrict__ ce_part)
{
    __shared__ unsigned int h[NENT];             // 1.5 KB
    __shared__ float cw[2][3];
    int t = threadIdx.x;
    #pragma unroll
    for (int i = t; i < NENT; i += 128) h[i] = 0u;
    __syncthreads();

    int g = blockIdx.x * 128 + t;                // 4-px group id (147456 total)
    int gx = g % 96;
    int row = g / 96;
    int y = row % 384;
    int b = row / 384;
    int x4 = gx * 4;

    const float scale = 95.0f / 383.0f;          // align_corners=True, 96 -> 384
    float sy = y * scale;
    int y0 = (int)sy; if (y0 > 94) y0 = 94;
    float ty = sy - (float)y0;
    float oty = 1.0f - ty;
    float sx0 = (float)x4 * scale;
    int X0 = (int)sx0; if (X0 > 92) X0 = 92;     // cols X0..X0+3 cover all 4 px

    // horizontal tent weights only (vertical blend factored out)
    float W[4][4];
    #pragma unroll
    for (int i = 0; i < 4; i++) {
        float sx = (float)(x4 + i) * scale;
        #pragma unroll
        for (int j = 0; j < 4; j++)
            W[i][j] = fmaxf(1.0f - fabsf(sx - (float)(X0 + j)), 0.0f);
    }

    const int rb = y0 * 96 + X0;

    // vertical-first bilinear: v_j shared across the 4 px (8 ops), then 4 FMA/px.
    auto interp4 = [&](const float* A, int c, float zout[4]) {
        float4a r0 = *(const float4a*)(A + c * 9216);
        float4a r1 = *(const float4a*)(A + c * 9216 + 96);
        float v0 = r0.x * oty + r1.x * ty;
        float v1 = r0.y * oty + r1.y * ty;
        float v2 = r0.z * oty + r1.z * ty;
        float v3 = r0.w * oty + r1.w * ty;
        #pragma unroll
        for (int i = 0; i < 4; i++)
            zout[i] = v0*W[i][0] + v1*W[i][1] + v2*W[i][2] + v3*W[i][3];
    };
    auto histadd = [&](int cls, int fg, float err) {
        int bk = (int)(err * (float)NBUCK);
        if (bk > NBUCK - 1) bk = NBUCK - 1;
        atomicAdd(&h[cls * NBUCK + bk], 0x10000u | (unsigned)fg);
    };

    float nll = 0.f, nll2 = 0.f; int vc = 0;

    int4 L0 = *(const int4*)(t0 + g * 4);
    int l0v[4] = {L0.x, L0.y, L0.z, L0.w};

    // |z| <= ~7 (bilinear blends of N(0,1)): exp of diffs overflow-safe in fp32.
    // ---- branch 0: 7 classes (CE + lovasz); softmax via diffs (6 exps/px) ----
    {
        const float* A0 = p0 + b * 7 * 9216 + rb;
        float z0[7][4];
        #pragma unroll
        for (int c = 0; c < 7; c++) interp4(A0, c, z0[c]);
        #pragma unroll
        for (int i = 0; i < 4; i++) {
            int l = l0v[i];
            if (l != IGNORE_LBL) {
                float e[7]; e[0] = 1.0f; float s = 1.0f;
                #pragma unroll
                for (int c = 1; c < 7; c++) { e[c] = __expf(z0[c][i] - z0[0][i]); s += e[c]; }
                float inv = 1.0f / s;
                float zl = z0[0][i];
                #pragma unroll
                for (int c = 1; c < 7; c++) zl = (l == c) ? z0[c][i] : zl;
                nll += __logf(s) - (zl - z0[0][i]);
                vc++;
                #pragma unroll
                for (int c = 0; c < 7; c++) {
                    int fg = (l == c);
                    histadd(c, fg, fabsf((float)fg - e[c] * inv));
                }
            }
        }
    }

    // ---- DSN: 7 classes, CE only, logsumexp via diffs (6 exps/px) ----
    {
        const float* Ad = pdsn + b * 7 * 9216 + rb;
        float zd[7][4];
        #pragma unroll
        for (int c = 0; c < 7; c++) interp4(Ad, c, zd[c]);
        #pragma unroll
        for (int i = 0; i < 4; i++) {
            int l = l0v[i];
            if (l != IGNORE_LBL) {
                float s = 1.0f;
                #pragma unroll
                for (int c = 1; c < 7; c++) s += __expf(zd[c][i] - zd[0][i]);
                float zl = zd[0][i];
                #pragma unroll
                for (int c = 1; c < 7; c++) zl = (l == c) ? zd[c][i] : zl;
                nll2 += __logf(s) - (zl - zd[0][i]);
            }
        }
    }

    // ---- branch 1: 3 classes (2 exps/px) ----
    {
        int4 L1 = *(const int4*)(t1 + g * 4);
        int l1v[4] = {L1.x, L1.y, L1.z, L1.w};
        const float* A1 = p1 + b * 3 * 9216 + rb;
        float z1[3][4];
        #pragma unroll
        for (int c = 0; c < 3; c++) interp4(A1, c, z1[c]);
        #pragma unroll
        for (int i = 0; i < 4; i++) {
            int l = l1v[i];
            if (l != IGNORE_LBL) {
                float e1 = __expf(z1[1][i] - z1[0][i]);
                float e2 = __expf(z1[2][i] - z1[0][i]);
                float inv = 1.0f / (1.0f + e1 + e2);
                histadd(7 + 0, (l == 0), fabsf((float)(l == 0) - inv));
                histadd(7 + 1, (l == 1), fabsf((float)(l == 1) - e1 * inv));
                histadd(7 + 2, (l == 2), fabsf((float)(l == 2) - e2 * inv));
            }
        }
    }

    // ---- branch 2: 2 classes, only class 10 stored (1 exp/px) ----
    {
        int4 L2 = *(const int4*)(t2 + g * 4);
        int l2v[4] = {L2.x, L2.y, L2.z, L2.w};
        const float* A2 = p2 + b * 2 * 9216 + rb;
        float z2a[2][4];
        #pragma unroll
        for (int c = 0; c < 2; c++) interp4(A2, c, z2a[c]);
        #pragma unroll
        for (int i = 0; i < 4; i++) {
            int l = l2v[i];
            if (l != IGNORE_LBL) {
                float p0c = 1.0f / (1.0f + __expf(z2a[1][i] - z2a[0][i]));
                histadd(10, (l == 0), fabsf((float)(l == 0) - p0c));
            }
        }
    }

    // ---- CE block reduce (2 waves) ----
    #pragma unroll
    for (int o = 32; o > 0; o >>= 1) {
        nll  += __shfl_down(nll, o);
        nll2 += __shfl_down(nll2, o);
        vc   += __shfl_down(vc, o);
    }
    int wv = t >> 6, ln = t & 63;
    if (ln == 0) { cw[wv][0] = nll; cw[wv][1] = nll2; cw[wv][2] = (float)vc; }
    __syncthreads();                                  // also fences all LDS atomics
    if (t == 0) {
        ce_part[blockIdx.x] = make_float4(cw[0][0] + cw[1][0],
                                          cw[0][1] + cw[1][1],
                                          cw[0][2] + cw[1][2], 0.f);
    }

    // ---- flush: skip-zero global atomics into 1-of-16 replicated histograms ----
    unsigned int* pp = pcnt + (size_t)(blockIdx.x & (NPART - 1)) * NENT;
    #pragma unroll
    for (int i = t; i < NENT; i += 128) {
        unsigned int v = h[i];
        if (v) atomicAdd(&pp[i], v);
    }
}

// single block: CE totals + ONE round of 16x32-wide segmented scan-walk + combine.
__global__ __launch_bounds__(512) void k_fin(
    const unsigned int* __restrict__ pcnt, const float4* __restrict__ ce_part,
    float* __restrict__ out)
{
    int t = threadIdx.x;
    __shared__ float ce_tot[3];
    __shared__ float cwf[8][3];
    __shared__ unsigned long long sc[512];
    __shared__ float sf[512];
    __shared__ float cls_lov[NCLS];
    __shared__ float cls_pres[NCLS];

    // Phase A: CE totals from per-block partials
    float a = 0.f, bb = 0.f, cc = 0.f;
    for (int e = t; e < NBMAIN; e += 512) {
        float4 v = ce_part[e];
        a += v.x; bb += v.y; cc += v.z;
    }
    #pragma unroll
    for (int o = 32; o > 0; o >>= 1) {
        a += __shfl_down(a, o); bb += __shfl_down(bb, o); cc += __shfl_down(cc, o);
    }
    if ((t & 63) == 0) { cwf[t >> 6][0] = a; cwf[t >> 6][1] = bb; cwf[t >> 6][2] = cc; }
    __syncthreads();
    if (t == 0) {
        float x = 0.f, y = 0.f, z = 0.f;
        for (int w = 0; w < 8; w++) { x += cwf[w][0]; y += cwf[w][1]; z += cwf[w][2]; }
        ce_tot[0] = x; ce_tot[1] = y; ce_tot[2] = z;
    }

    // Phase B: lovasz walk, all 12 classes in one round (16 segments x 32 threads)
    int sub = t >> 5;                 // segment 0..15 (12..15 idle)
    int p   = t & 31;                 // position in segment
    int bk  = NBUCK - 1 - p;          // descending bucket

    int kk = sub;
    unsigned int cnt = 0, fg = 0;
    if (kk < NCLS) {
        int src = (kk == 11) ? 10 : kk;          // class 11 derived from class 10
        #pragma unroll
        for (int cy = 0; cy < NPART; cy++) {
            unsigned int v = pcnt[(size_t)cy * NENT + src * NBUCK + bk];
            cnt += v >> 16; fg += v & 0xffffu;
        }
        if (kk == 11) fg = cnt - fg;
    }
    unsigned long long own = ((unsigned long long)cnt << 32) | fg;
    sc[t] = own;
    __syncthreads();
    #pragma unroll
    for (int o = 1; o < 32; o <<= 1) {
        unsigned long long add = (p >= o) ? sc[t - o] : 0ull;
        __syncthreads();
        sc[t] += add;
        __syncthreads();
    }
    unsigned long long total = sc[(sub << 5) + 31];
    unsigned long long excl = sc[t] - own;
    unsigned int G = (unsigned int)(total & 0xffffffffu);

    float contrib = 0.f;
    if (G > 0 && cnt > 0) {
        unsigned int rr = (unsigned int)(excl >> 32);
        unsigned int F  = (unsigned int)(excl & 0xffffffffu);
        float fG = (float)G;
        float j0 = 1.0f - (fG - (float)F) / fmaxf(fG + (float)rr - (float)F, 1.0f);
        rr += cnt; F += fg;
        float j1 = 1.0f - (fG - (float)F) / fmaxf(fG + (float)rr - (float)F, 1.0f);
        contrib = (((float)bk + 0.5f) * (1.0f / (float)NBUCK)) * (j1 - j0);
    }
    sf[t] = contrib;
    __syncthreads();
    #pragma unroll
    for (int o = 16; o > 0; o >>= 1) {
        if (p < o) sf[t] += sf[t + o];
        __syncthreads();
    }
    if (p == 0 && kk < NCLS) {
        cls_lov[kk]  = (G > 0) ? sf[t] : 0.f;
        cls_pres[kk] = (G > 0) ? 1.f : 0.f;
    }
    __syncthreads();

    if (t == 0) {
        float l0 = 0.f, p0c = 0.f, l1 = 0.f, p1c = 0.f, l2 = 0.f, p2c = 0.f;
        for (int k = 0; k < 7;  k++) { l0 += cls_lov[k]; p0c += cls_pres[k]; }
        for (int k = 7; k < 10; k++) { l1 += cls_lov[k]; p1c += cls_pres[k]; }
        for (int k = 10; k < 12; k++) { l2 += cls_lov[k]; p2c += cls_pres[k]; }
        float vcnt = fmaxf(ce_tot[2], 1.0f);
        out[0] = ce_tot[0] / vcnt
               + l0 / fmaxf(p0c, 1.f)
               + 0.4f * (l1 / fmaxf(p1c, 1.f))
               + 0.4f * (l2 / fmaxf(p2c, 1.f))
               + 0.4f * (ce_tot[1] / vcnt);
    }
}

extern "C" void kernel_launch(void* const* d_in, const int* in_sizes, int n_in,
                              void* d_out, int out_size, void* d_ws, size_t ws_size,
                              hipStream_t stream)
{
    const float* p0 = (const float*)d_in[0];   // [4,7,96,96]
    const float* p1 = (const float*)d_in[1];   // [4,3,96,96]
    const float* p2 = (const float*)d_in[2];   // [4,2,96,96]
    const float* pd = (const float*)d_in[3];   // [4,7,96,96]
    const int* t0 = (const int*)d_in[4];       // [4,384,384]
    const int* t1 = (const int*)d_in[5];
    const int* t2 = (const int*)d_in[6];

    char* ws = (char*)d_ws;
    const size_t pcnt_bytes = (size_t)NPART * NENT * 4;                 // 24,576
    unsigned int* pcnt = (unsigned int*)ws;
    float4* ce_part = (float4*)(ws + pcnt_bytes);

    hipMemsetAsync(d_ws, 0, pcnt_bytes, stream);   // zero the atomic histograms

    k_main<<<NBMAIN, 128, 0, stream>>>(p0, p1, p2, pd, t0, t1, t2, pcnt, ce_part);
    k_fin<<<1, 512, 0, stream>>>(pcnt, ce_part, (float*)d_out);
}